// Round 10
// baseline (371.368 us; speedup 1.0000x reference)
//
#include <hip/hip_runtime.h>
#include <hip/hip_bf16.h>

// Problem constants (B,L,H,D) = (8,2048,8,64); sample_k = u = 40.
#define BB 8
#define LL 2048
#define HH 8
#define DD 64
#define HD 512      // H*D
#define SK 40       // sample_k
#define UU 40       // top-u
#define NCHUNK 16   // key chunks for flash-decode
#define CHUNK 128   // keys per chunk
#define PSTR 132    // transposed P row stride (floats), 16B-aligned

typedef float v4f __attribute__((ext_vector_type(4)));

// ---------------- workspace layout (bytes) ----------------
static const size_t OFF_M     = 0;                 // B*H*L floats   = 512 KB
static const size_t OFF_TOP   = 512ull * 1024;     // B*H*40 ints    = 10 KB
static const size_t OFF_VPART = 592ull * 1024;     // 8*B*H*64 floats= 128 KB
static const size_t OFF_MPART = 768ull * 1024;     // B*H*40*16      = 160 KB
static const size_t OFF_SPART = 960ull * 1024;     // B*H*40*16      = 160 KB
static const size_t OFF_OPART = 1152ull * 1024;    // B*H*40*16*64   = 10 MB

// ---- DPP helpers (all ctrl args must be ICE -> templates) ----
template <int CTRL>
__device__ __forceinline__ float dpp_add(float x) {
    int yi = __builtin_amdgcn_mov_dpp(__float_as_int(x), CTRL, 0xF, 0xF, true);
    return x + __int_as_float(yi);
}
// max step: invalid source lanes keep old(=x); fmax(x,x)=x safe.
template <int CTRL>
__device__ __forceinline__ float dpp_max_step(float x) {
    int yi = __builtin_amdgcn_update_dpp(__float_as_int(x), __float_as_int(x),
                                         CTRL, 0xF, 0xF, false);
    return fmaxf(x, __int_as_float(yi));
}
// sum step: invalid source lanes contribute old=0.
template <int CTRL>
__device__ __forceinline__ float dpp_sum_step(float x) {
    int yi = __builtin_amdgcn_update_dpp(0, __float_as_int(x),
                                         CTRL, 0xF, 0xF, false);
    return x + __int_as_float(yi);
}
// full-wave reduce; result valid in lane 63, fetched via readlane.
__device__ __forceinline__ float wave_max64(float x) {
    x = dpp_max_step<0xB1>(x);   // xor1
    x = dpp_max_step<0x4E>(x);   // xor2
    x = dpp_max_step<0x141>(x);  // half_mirror (xor4)
    x = dpp_max_step<0x140>(x);  // mirror (xor8)
    x = dpp_max_step<0x142>(x);  // row_bcast15
    x = dpp_max_step<0x143>(x);  // row_bcast31
    return __int_as_float(__builtin_amdgcn_readlane(__float_as_int(x), 63));
}
__device__ __forceinline__ float wave_sum64(float x) {
    x = dpp_sum_step<0xB1>(x);
    x = dpp_sum_step<0x4E>(x);
    x = dpp_sum_step<0x141>(x);
    x = dpp_sum_step<0x140>(x);
    x = dpp_sum_step<0x142>(x);
    x = dpp_sum_step<0x143>(x);
    return __int_as_float(__builtin_amdgcn_readlane(__float_as_int(x), 63));
}

// ============ kernel A v3 (round-8 proven, unroll 8): M = max_s - mean_s ============
__global__ __launch_bounds__(128) void kA_sample_scores(
    const float* __restrict__ Q, const float* __restrict__ K,
    const int* __restrict__ IS, float* __restrict__ M)
{
    int blk = blockIdx.x;
    int b = blk & 7;                 // XCD pin: batch b -> XCD b (K[b]=4MB==L2)
    int q = blk >> 3;
    int tid = threadIdx.x;
    int h = tid >> 4;
    int lane = tid & 15;

    const int* __restrict__ isq = IS + q * SK;   // block-uniform
    size_t base = (size_t)b * LL * HD;
    int off = h * DD + lane * 4;
    v4f qv = __builtin_nontemporal_load(
        (const v4f*)(Q + base + (size_t)q * HD + off));
    const float* __restrict__ Kb = K + base;

    float mx = -1e30f, sm = 0.f;
#pragma unroll 8
    for (int s = 0; s < SK; ++s) {
        int idx = __builtin_amdgcn_readfirstlane(isq[s]);   // SGPR index
        const float* __restrict__ Krow = Kb + (size_t)idx * HD;
        const float4 kv = *(const float4*)(Krow + off);
        float p = qv.x * kv.x + qv.y * kv.y + qv.z * kv.z + qv.w * kv.w;
        p = dpp_add<0xB1>(p);
        p = dpp_add<0x4E>(p);
        p = dpp_add<0x141>(p);
        p = dpp_add<0x140>(p);
        mx = fmaxf(mx, p);
        sm += p;
    }
    if (lane == 0)
        M[((size_t)(b * HH + h)) * LL + q] = mx - sm * (1.0f / SK);
}

// ============ kernel B: top-40 of M[bh,:] via 3-level parallel radix select ============
__global__ __launch_bounds__(256) void kB_topk(
    const float* __restrict__ M, int* __restrict__ TopIdx)
{
    int bh = blockIdx.x;
    int tid = threadIdx.x;
    __shared__ unsigned keys[LL];
    __shared__ int      hist[4096];
    __shared__ int      sscan[256];
    __shared__ unsigned ckeyA[2048];
    __shared__ int      cidxA[2048];
    __shared__ unsigned ckeyB[2048];
    __shared__ int      cidxB[2048];
    __shared__ int ctr[8]; // 0:sel 1:nA 2:nB 3:T 4:kprime 5:nExact

    const float* __restrict__ m = M + (size_t)bh * LL;
    for (int i = tid; i < 4096; i += 256) hist[i] = 0;
    if (tid < 8) ctr[tid] = 0;
    __syncthreads();

    for (int i = tid; i < LL; i += 256) {
        unsigned u = __float_as_uint(m[i]);
        u = (u & 0x80000000u) ? ~u : (u | 0x80000000u);
        keys[i] = u;
        atomicAdd(&hist[u >> 20], 1);
    }
    __syncthreads();
    {
        int p = 0;
#pragma unroll
        for (int j = 0; j < 16; ++j) p += hist[tid * 16 + j];
        sscan[tid] = p;
        __syncthreads();
        for (int o = 1; o < 256; o <<= 1) {
            int v = (tid + o < 256) ? sscan[tid + o] : 0;
            __syncthreads();
            sscan[tid] += v;
            __syncthreads();
        }
        int snext = (tid < 255) ? sscan[tid + 1] : 0;
        if (sscan[tid] >= UU && snext < UU) {
            int cum = snext;
            for (int bkt = tid * 16 + 15; bkt >= tid * 16; --bkt) {
                int c = hist[bkt];
                if (cum + c >= UU) { ctr[3] = bkt; ctr[4] = UU - cum; break; }
                cum += c;
            }
        }
    }
    __syncthreads();
    unsigned T1 = (unsigned)ctr[3];
    int k1 = ctr[4];
    for (int i = tid; i < LL; i += 256) {
        unsigned u = keys[i];
        unsigned bkt = u >> 20;
        if (bkt > T1) {
            int p = atomicAdd(&ctr[0], 1);
            TopIdx[bh * UU + p] = i;
        } else if (bkt == T1) {
            int p = atomicAdd(&ctr[1], 1);
            ckeyA[p] = u; cidxA[p] = i;
        }
    }
    __syncthreads();
    int nA = ctr[1];

    for (int i = tid; i < 4096; i += 256) hist[i] = 0;
    __syncthreads();
    for (int i = tid; i < nA; i += 256)
        atomicAdd(&hist[(ckeyA[i] >> 8) & 0xFFF], 1);
    __syncthreads();
    {
        int p = 0;
#pragma unroll
        for (int j = 0; j < 16; ++j) p += hist[tid * 16 + j];
        sscan[tid] = p;
        __syncthreads();
        for (int o = 1; o < 256; o <<= 1) {
            int v = (tid + o < 256) ? sscan[tid + o] : 0;
            __syncthreads();
            sscan[tid] += v;
            __syncthreads();
        }
        int snext = (tid < 255) ? sscan[tid + 1] : 0;
        if (sscan[tid] >= k1 && snext < k1) {
            int cum = snext;
            for (int bkt = tid * 16 + 15; bkt >= tid * 16; --bkt) {
                int c = hist[bkt];
                if (cum + c >= k1) { ctr[3] = bkt; ctr[4] = k1 - cum; break; }
                cum += c;
            }
        }
    }
    __syncthreads();
    unsigned T2 = (unsigned)ctr[3];
    int k2 = ctr[4];
    for (int i = tid; i < nA; i += 256) {
        unsigned u = ckeyA[i];
        unsigned bkt = (u >> 8) & 0xFFF;
        if (bkt > T2) {
            int p = atomicAdd(&ctr[0], 1);
            TopIdx[bh * UU + p] = cidxA[i];
        } else if (bkt == T2) {
            int p = atomicAdd(&ctr[2], 1);
            ckeyB[p] = u; cidxB[p] = cidxA[i];
        }
    }
    __syncthreads();
    int nB = ctr[2];

    for (int i = tid; i < 256; i += 256) hist[i] = 0;
    __syncthreads();
    for (int i = tid; i < nB; i += 256)
        atomicAdd(&hist[ckeyB[i] & 0xFF], 1);
    __syncthreads();
    {
        sscan[tid] = hist[tid];
        __syncthreads();
        for (int o = 1; o < 256; o <<= 1) {
            int v = (tid + o < 256) ? sscan[tid + o] : 0;
            __syncthreads();
            sscan[tid] += v;
            __syncthreads();
        }
        int snext = (tid < 255) ? sscan[tid + 1] : 0;
        if (sscan[tid] >= k2 && snext < k2) { ctr[3] = tid; ctr[4] = k2 - snext; }
    }
    __syncthreads();
    unsigned T3 = (unsigned)ctr[3];
    int k3 = ctr[4];
    for (int i = tid; i < nB; i += 256) {
        unsigned u = ckeyB[i];
        unsigned bkt = u & 0xFF;
        if (bkt > T3) {
            int p = atomicAdd(&ctr[0], 1);
            TopIdx[bh * UU + p] = cidxB[i];
        } else if (bkt == T3) {
            int p = atomicAdd(&ctr[5], 1);
            cidxA[p] = cidxB[i];
        }
    }
    __syncthreads();
    if (tid == 0) {
        int n = ctr[5];
        int basep = ctr[0];
        for (int r = 0; r < k3; ++r) {
            int bi = 1 << 30, bp = -1;
            for (int j = 0; j < n; ++j) {
                int id = cidxA[j];
                if (id >= 0 && id < bi) { bi = id; bp = j; }
            }
            TopIdx[bh * UU + basep + r] = bi;
            cidxA[bp] = -1;
        }
    }
}

// ============ kernel C: V partial column-sums (float4 coalesced) ============
__global__ __launch_bounds__(256) void kC_vmean(
    const float* __restrict__ V, float* __restrict__ Vpart)
{
    int bh = blockIdx.x >> 3;
    int ch = blockIdx.x & 7;
    int b = bh >> 3, h = bh & 7;
    int tid = threadIdx.x;
    int dq = tid & 15;
    int lg = tid >> 4;

    float4 acc = make_float4(0.f, 0.f, 0.f, 0.f);
    size_t base = ((size_t)b * LL + ch * 256) * HD + h * DD + dq * 4;
    for (int l = lg; l < 256; l += 16) {
        float4 v = *(const float4*)(V + base + (size_t)l * HD);
        acc.x += v.x; acc.y += v.y; acc.z += v.z; acc.w += v.w;
    }
    __shared__ float4 red[256];
    red[tid] = acc;
    __syncthreads();
    if (tid < 16) {
        float4 s = make_float4(0.f, 0.f, 0.f, 0.f);
#pragma unroll
        for (int g = 0; g < 16; ++g) {
            float4 v = red[g * 16 + tid];
            s.x += v.x; s.y += v.y; s.z += v.z; s.w += v.w;
        }
        *(float4*)(Vpart + ch * 4096 + bh * 64 + tid * 4) = s;
    }
}

// ============ kernel D: fill all output rows with mean(V)/L ============
__global__ __launch_bounds__(256) void kD_fill(
    const float* __restrict__ Vpart, float* __restrict__ out)
{
    size_t i4 = (size_t)blockIdx.x * 256 + threadIdx.x;
    size_t o = i4 * 4;
    int hd = (int)(o & (HD - 1));
    int b  = (int)(o >> 20);
    int h  = hd >> 6;
    int idx = (b * HH + h) * DD + (hd & 63);
    float4 acc = make_float4(0.f, 0.f, 0.f, 0.f);
#pragma unroll
    for (int c = 0; c < 8; ++c) {
        float4 v = *(const float4*)(Vpart + c * 4096 + idx);
        acc.x += v.x; acc.y += v.y; acc.z += v.z; acc.w += v.w;
    }
    const float sc = 1.0f / LL;
    float4 r; r.x = acc.x * sc; r.y = acc.y * sc; r.z = acc.z * sc; r.w = acc.w * sc;
    *(float4*)(out + o) = r;
}

// ============ kernel E v6: flash-decode partials, LDS-pipe-lean ============
// grid = (NCHUNK, B*H), block 256 = 4 waves. Wave w owns u in [w*10, w*10+10)
// and all 128 l (2 per lane) -> per-u softmax reductions are wave-local DPP
// (VALU pipe, no LDS). P stored transposed [u][l] (stride 132) so PV reads
// are broadcast ds_read_b128. Two barriers total.
__global__ __launch_bounds__(256) void kE_attn_partial(
    const float* __restrict__ Q, const float* __restrict__ K, const float* __restrict__ V,
    const int* __restrict__ TopIdx,
    float* __restrict__ Opart, float* __restrict__ mpart, float* __restrict__ spart)
{
    int c  = blockIdx.x;
    int bh = blockIdx.y;
    int b = bh >> 3, h = bh & 7;
    int tid = threadIdx.x;

    __shared__ float Qs[UU * DD];          // 10 KB
    __shared__ float P[UU * PSTR];         // 20.6 KB, transposed [u][l]
    __shared__ int   qidx[UU];
    __shared__ float mred[UU], sred[UU];

    if (tid < UU) qidx[tid] = TopIdx[bh * UU + tid];
    __syncthreads();   // also covers Qs stage below via next barrier

    size_t hbase  = (size_t)b * LL * HD + h * DD;
    size_t kcbase = hbase + (size_t)c * CHUNK * HD;

    for (int r = tid; r < UU * 16; r += 256) {
        int u = r >> 4, j = r & 15;
        *(float4*)(Qs + u * DD + j * 4) =
            *(const float4*)(Q + hbase + (size_t)qidx[u] * HD + j * 4);
    }
    __syncthreads();

    // ---- scores + wave-local softmax ----
    {
        int lt = tid & 63;          // l-thread: handles l = lt and lt+64
        int ug = tid >> 6;          // wave id: u in [ug*10, ug*10+10)
        const float* __restrict__ Krow0 = K + kcbase + (size_t)lt * HD;
        const float* __restrict__ Krow1 = Krow0 + 64 * HD;
        float dot0[10], dot1[10];
#pragma unroll
        for (int i = 0; i < 10; ++i) { dot0[i] = 0.f; dot1[i] = 0.f; }

#pragma unroll
        for (int half = 0; half < 2; ++half) {
            float4 kr0[8], kr1[8];
#pragma unroll
            for (int j = 0; j < 8; ++j) {
                kr0[j] = *(const float4*)(Krow0 + half * 32 + j * 4);
                kr1[j] = *(const float4*)(Krow1 + half * 32 + j * 4);
            }
#pragma unroll
            for (int j = 0; j < 8; ++j) {
                float4 k0 = kr0[j], k1 = kr1[j];
#pragma unroll
                for (int uu = 0; uu < 10; ++uu) {
                    float4 qv = *(const float4*)(Qs + (ug * 10 + uu) * DD + half * 32 + j * 4);
                    dot0[uu] += k0.x * qv.x + k0.y * qv.y + k0.z * qv.z + k0.w * qv.w;
                    dot1[uu] += k1.x * qv.x + k1.y * qv.y + k1.z * qv.z + k1.w * qv.w;
                }
            }
        }

#pragma unroll
        for (int uu = 0; uu < 10; ++uu) {
            int u = ug * 10 + uu;
            float d0 = dot0[uu] * 0.125f;   // 1/sqrt(64)
            float d1 = dot1[uu] * 0.125f;
            float m = wave_max64(fmaxf(d0, d1));      // wave-uniform
            float p0 = __expf(d0 - m);
            float p1 = __expf(d1 - m);
            P[u * PSTR + lt]      = p0;
            P[u * PSTR + lt + 64] = p1;
            float s = wave_sum64(p0 + p1);            // wave-uniform
            if (lt == 0) { mred[u] = m; sred[u] = s; }
        }
    }
    __syncthreads();   // P, mred, sred complete

    // ---- PV: thread (dq = tid&15 -> d=dq*4, ug4 = tid>>4); u = ug4 + 16i ----
    {
        int dq = tid & 15, ug4 = tid >> 4;
        float4 acc[3];
#pragma unroll
        for (int i = 0; i < 3; ++i) acc[i] = make_float4(0.f, 0.f, 0.f, 0.f);
        const float* __restrict__ Vb = V + kcbase + dq * 4;
        for (int l0 = 0; l0 < CHUNK; l0 += 8) {
            float4 v[8];
#pragma unroll
            for (int j = 0; j < 8; ++j)
                v[j] = *(const float4*)(Vb + (size_t)(l0 + j) * HD);
#pragma unroll
            for (int i = 0; i < 3; ++i) {
                int u = ug4 + 16 * i;
                if (u < UU) {
                    // broadcast b128 reads of exp'd P row
                    float4 pa = *(const float4*)(P + u * PSTR + l0);
                    float4 pb = *(const float4*)(P + u * PSTR + l0 + 4);
                    acc[i].x += pa.x * v[0].x; acc[i].y += pa.x * v[0].y;
                    acc[i].z += pa.x * v[0].z; acc[i].w += pa.x * v[0].w;
                    acc[i].x += pa.y * v[1].x; acc[i].y += pa.y * v[1].y;
                    acc[i].z += pa.y * v[1].z; acc[i].w += pa.y * v[1].w;
                    acc[i].x += pa.z * v[2].x; acc[i].y += pa.z * v[2].y;
                    acc[i].z += pa.z * v[2].z; acc[i].w += pa.z * v[2].w;
                    acc[i].x += pa.w * v[3].x; acc[i].y += pa.w * v[3].y;
                    acc[i].z += pa.w * v[3].z; acc[i].w += pa.w * v[3].w;
                    acc[i].x += pb.x * v[4].x; acc[i].y += pb.x * v[4].y;
                    acc[i].z += pb.x * v[4].z; acc[i].w += pb.x * v[4].w;
                    acc[i].x += pb.y * v[5].x; acc[i].y += pb.y * v[5].y;
                    acc[i].z += pb.y * v[5].z; acc[i].w += pb.y * v[5].w;
                    acc[i].x += pb.z * v[6].x; acc[i].y += pb.z * v[6].y;
                    acc[i].z += pb.z * v[6].z; acc[i].w += pb.z * v[6].w;
                    acc[i].x += pb.w * v[7].x; acc[i].y += pb.w * v[7].y;
                    acc[i].z += pb.w * v[7].z; acc[i].w += pb.w * v[7].w;
                }
            }
        }
#pragma unroll
        for (int i = 0; i < 3; ++i) {
            int u = ug4 + 16 * i;
            if (u < UU) {
                size_t ob = (((size_t)(bh * UU + u)) * NCHUNK + c) * DD + dq * 4;
                *(float4*)(Opart + ob) = acc[i];
            }
        }
    }
    if (tid < UU) {
        mpart[(bh * UU + tid) * NCHUNK + c] = mred[tid];
        spart[(bh * UU + tid) * NCHUNK + c] = sred[tid];
    }
}

// ============ kernel F: combine chunk partials, scatter into output ============
__global__ __launch_bounds__(64) void kF_combine(
    const float* __restrict__ Opart, const float* __restrict__ mpart,
    const float* __restrict__ spart, const int* __restrict__ TopIdx,
    float* __restrict__ out)
{
    int g = blockIdx.x;            // bh*40 + u
    int bh = g / UU;
    int b = bh >> 3, h = bh & 7;
    int d = threadIdx.x;

    float m_i[NCHUNK];
    float Mx = -1e30f;
#pragma unroll
    for (int i = 0; i < NCHUNK; ++i) { m_i[i] = mpart[g * NCHUNK + i]; Mx = fmaxf(Mx, m_i[i]); }
    float S = 0.f, O = 0.f;
#pragma unroll
    for (int i = 0; i < NCHUNK; ++i) {
        float w = __expf(m_i[i] - Mx);
        S += w * spart[g * NCHUNK + i];
        O += w * Opart[((size_t)g * NCHUNK + i) * DD + d];
    }
    int qi = TopIdx[g];
    out[((size_t)b * LL + qi) * HD + h * DD + d] = O / S;
}

extern "C" void kernel_launch(void* const* d_in, const int* in_sizes, int n_in,
                              void* d_out, int out_size, void* d_ws, size_t ws_size,
                              hipStream_t stream) {
    const float* Q  = (const float*)d_in[0];
    const float* K  = (const float*)d_in[1];
    const float* V  = (const float*)d_in[2];
    const int*   IS = (const int*)d_in[3];
    float* out = (float*)d_out;
    char* ws = (char*)d_ws;

    float* M      = (float*)(ws + OFF_M);
    int*   TopIdx = (int*)(ws + OFF_TOP);
    float* Vpart  = (float*)(ws + OFF_VPART);
    float* mpart  = (float*)(ws + OFF_MPART);
    float* spart  = (float*)(ws + OFF_SPART);
    float* Opart  = (float*)(ws + OFF_OPART);

    kA_sample_scores<<<BB * LL, 128, 0, stream>>>(Q, K, IS, M);
    kC_vmean<<<BB * HH * 8, 256, 0, stream>>>(V, Vpart);
    kB_topk<<<BB * HH, 256, 0, stream>>>(M, TopIdx);
    kD_fill<<<(BB * LL * HD) / (256 * 4), 256, 0, stream>>>(Vpart, out);
    kE_attn_partial<<<dim3(NCHUNK, BB * HH), 256, 0, stream>>>(Q, K, V, TopIdx,
                                                               Opart, mpart, spart);
    kF_combine<<<BB * HH * UU, 64, 0, stream>>>(Opart, mpart, spart, TopIdx, out);
}